// Round 8
// baseline (2143.069 us; speedup 1.0000x reference)
//
#include <hip/hip_runtime.h>

#define H 1024
#define I_DIM 128
#define O_DIM 128
#define T_DIM 512
#define ALPHA 0.2f
#define NWG 64              // 8 batch-groups x 8 j-slices; group g = bids {g, g+8, ...}
#define PLANE_U64 1024      // 32 slices x 32 octets, one u64 chunk each
#define PAR_U64   3072      // 3 planes per parity
#define GRPA_U64  6144      // 2 parities per group
#define ARENA_U64 49152     // 8 * GRPA_U64 = 384 KiB exactly (R1-R5-proven footprint)

typedef short short8 __attribute__((ext_vector_type(8)));
typedef float f32x4 __attribute__((ext_vector_type(4)));
typedef unsigned long long u64;
typedef unsigned long long ull_alias __attribute__((may_alias));

__device__ __forceinline__ unsigned short f2b(float f) {
    union { float f; unsigned u; } x; x.f = f;
    unsigned u = x.u;
    return (unsigned short)((u + 0x7FFFu + ((u >> 16) & 1u)) >> 16);
}
__device__ __forceinline__ float tanh_fast(float x) {
    float e = __expf(2.0f * x);
    return 1.0f - 2.0f * __builtin_amdgcn_rcpf(e + 1.0f);
}
__device__ __forceinline__ short8 ld8f(const float* __restrict__ p) {
    const float4 a = *(const float4*)p;
    const float4 b = *(const float4*)(p + 4);
    short8 r;
    r[0]=(short)f2b(a.x); r[1]=(short)f2b(a.y); r[2]=(short)f2b(a.z); r[3]=(short)f2b(a.w);
    r[4]=(short)f2b(b.x); r[5]=(short)f2b(b.y); r[6]=(short)f2b(b.z); r[7]=(short)f2b(b.w);
    return r;
}
__device__ __forceinline__ short8 pack8(float4 a, float4 b) {
    short8 r;
    r[0]=(short)f2b(a.x); r[1]=(short)f2b(a.y); r[2]=(short)f2b(a.z); r[3]=(short)f2b(a.w);
    r[4]=(short)f2b(b.x); r[5]=(short)f2b(b.y); r[6]=(short)f2b(b.z); r[7]=(short)f2b(b.w);
    return r;
}
// LDS-only barrier (no vmcnt drain): every barrier here hands off LDS only.
// Proven in the passing R5 build.
__device__ __forceinline__ void bar_lgkm() {
    asm volatile("s_waitcnt lgkmcnt(0)\n\ts_barrier" ::: "memory");
}

// abuf packed-A (8 batch rows): u16 off(k,m) = (k>>5)*256 + ((k>>3)&3)*64 + (m&7)*8 + (k&7)
// Slice s = ji*4+w covers k in [s*32,+32). Octet o = m*4 + (klocal>>3) = 8 u16 of one row.
// Chunk(s,o,p) at plane_p[s*32+o]: 48b data (3 bf16) + 16b step tag, self-validating.
// All arena traffic via relaxed agent-scope atomics (the R5-proven protocol).
// R8 tests ONLY the geometry: 8 groups x 8 WGs (convoy 16->8, consume volume
// halved, out-GEMM fused into the wrec K-loop, 2 barriers/step).
__global__ __launch_bounds__(256, 1) void rnn_kernel(
    const float* __restrict__ x, const float* __restrict__ wi,
    const float* __restrict__ wrec, const float* __restrict__ wout,
    const float* __restrict__ bb, const float* __restrict__ gg,
    const float* __restrict__ h0p, float* __restrict__ out,
    u64* __restrict__ aG)
{
    __shared__ unsigned short abuf[8192];   // 16 KB: group's a_{t-1}, 8 rows x 1024 k
    __shared__ unsigned short aloc[1024];   // 2 KB: own a_t slice (wave-private slabs)
    __shared__ float opart[512];            // 2 KB: out k-partials

    const int tid  = threadIdx.x;
    const int w    = tid >> 6, lane = tid & 63;
    const int q    = lane >> 4;             // frag k-octet selector (0..3)
    const int n16  = lane & 15;
    const int mm8  = lane & 7;              // batch row for A-frags (rows 8-15 duplicate)
    const int q2   = (lane >> 4) & 1;
    const int b3   = (lane >> 3) & 1;
    const int grp  = (int)blockIdx.x & 7;
    const int ji   = (int)blockIdx.x >> 3;
    const int b0   = grp * 8;
    const int jb   = ji * 128 + w * 32;
    const int s_sl = ji * 4 + w;
    const int cbg  = w * 256 + lane;        // consume octet-index base

    u64* const gB = aG + (size_t)grp * GRPA_U64;

    // ---- register-resident weights ----
    short8 wfr[64];                              // wrec B-frags [nt*32+kt]
#pragma unroll
    for (int nt = 0; nt < 2; ++nt)
#pragma unroll
        for (int kt = 0; kt < 32; ++kt)
            wfr[nt * 32 + kt] = ld8f(&wrec[(size_t)(jb + nt * 16 + n16) * H + kt * 32 + q * 8]);

    short8 wifr[8];                              // wi B-frags [nt*4+kt]
#pragma unroll
    for (int nt = 0; nt < 2; ++nt)
#pragma unroll
        for (int kt = 0; kt < 4; ++kt) {
            short8 v;
#pragma unroll
            for (int i = 0; i < 8; ++i)
                v[i] = (short)f2b(wi[(size_t)(kt * 32 + q * 8 + i) * H + jb + nt * 16 + n16]);
            wifr[nt * 4 + kt] = v;
        }
    short8 wofr[8];                              // wout B-frags, cols ji*16..+16
#pragma unroll
    for (int kk = 0; kk < 8; ++kk) {
        short8 v;
        const int kb = (w * 8 + kk) * 32 + q * 8;
#pragma unroll
        for (int i = 0; i < 8; ++i)
            v[i] = (short)f2b(wout[(size_t)(kb + i) * O_DIM + ji * 16 + n16]);
        wofr[kk] = v;
    }

    float gvv[2], bvv[2], hreg[8];
#pragma unroll
    for (int nt = 0; nt < 2; ++nt) {
        const int j = jb + nt * 16 + n16;
        gvv[nt] = gg[j]; bvv[nt] = bb[j];
        const float h00 = h0p[j];
#pragma unroll
        for (int r = 0; r < 4; ++r) hreg[nt * 4 + r] = h00;
    }

    short8 xfr[4];                               // packed x[:,0,:]
#pragma unroll
    for (int kt = 0; kt < 4; ++kt)
        xfr[kt] = ld8f(&x[(size_t)(b0 + mm8) * T_DIM * I_DIM + kt * 32 + q * 8]);

    // a0 staging (batch-broadcast). Octet O = m*4 + nt*2 + b3, element e = n16&7.
    // Valid accumulator rows live in lanes < 32 (m = q2*4 + r).
    if (lane < 32) {
#pragma unroll
        for (int nt = 0; nt < 2; ++nt) {
            const unsigned short a0 = f2b(gvv[nt] * tanh_fast(hreg[nt * 4] + bvv[nt]));
#pragma unroll
            for (int r = 0; r < 4; ++r)
                aloc[w * 256 + ((4 * q2 + r) * 4 + nt * 2 + b3) * 8 + mm8] = a0;
        }
    }

    u64 pv0[4], pv1[4], pv2[4];

    auto poll_issue = [&](const u64* gb) {
#pragma unroll
        for (int i = 0; i < 4; ++i) {
            pv0[i] = __hip_atomic_load(gb + cbg + i * 64,
                                       __ATOMIC_RELAXED, __HIP_MEMORY_SCOPE_AGENT);
            pv1[i] = __hip_atomic_load(gb + PLANE_U64 + cbg + i * 64,
                                       __ATOMIC_RELAXED, __HIP_MEMORY_SCOPE_AGENT);
            pv2[i] = __hip_atomic_load(gb + 2 * PLANE_U64 + cbg + i * 64,
                                       __ATOMIC_RELAXED, __HIP_MEMORY_SCOPE_AGENT);
        }
    };
    auto poll_check = [&](int tv, const u64* gb) {
        const unsigned tt = (unsigned)tv;
        for (;;) {
            unsigned bad = 0;
#pragma unroll
            for (int i = 0; i < 4; ++i)
                bad |= ((unsigned)(pv0[i] >> 48) ^ tt) | ((unsigned)(pv1[i] >> 48) ^ tt)
                     | ((unsigned)(pv2[i] >> 48) ^ tt);
            if (__all(bad == 0)) break;
            __builtin_amdgcn_s_sleep(1);
            poll_issue(gb);
        }
        asm volatile("" ::: "memory");
    };
    auto unpack = [&]() {
#pragma unroll
        for (int i = 0; i < 4; ++i) {
            const int g  = cbg + i * 64;
            const int db = ((g >> 5) << 9) | ((g & 3) << 7) | (((g >> 2) & 7) << 4);
            const u64 ca = pv0[i], cb_ = pv1[i], cc = pv2[i];
            const u64 w01 = (ca & 0xFFFFFFFFull)
                | (((ca >> 32) & 0xFFFFull) << 32) | ((cb_ & 0xFFFFull) << 48);   // el 0..3
            const u64 w23 = ((cb_ >> 16) & 0xFFFFFFFFull) | (cc << 32);           // el 4..7
            ull_alias* d = (ull_alias*)((char*)abuf + db);
            d[0] = w01; d[1] = w23;
        }
    };
    auto publish = [&](int t) {
        asm volatile("s_waitcnt lgkmcnt(0)" ::: "memory");   // own-wave aloc writes done
        const u64 tagv = (u64)(unsigned)t << 48;
        u64* gb = gB + ((t & 1) ? PAR_U64 : 0);
        const ull_alias* opq = (const ull_alias*)&aloc[w * 256 + (lane & 31) * 8];
        const u64 lo = opq[0], hi = opq[1];
        const u64 d01 = (lane < 32) ? (lo & 0x0000FFFFFFFFFFFFull)
                                    : (((lo >> 48) | (hi << 16)) & 0x0000FFFFFFFFFFFFull);
        u64* pA = gb + (lane >> 5) * PLANE_U64 + s_sl * 32 + (lane & 31);
        __hip_atomic_store(pA, d01 | tagv, __ATOMIC_RELAXED, __HIP_MEMORY_SCOPE_AGENT);
        if (lane < 32) {
            const u64 d2 = ((hi >> 32) & 0xFFFFFFFFull) | tagv;   // el 6,7 + tag
            u64* pB = gb + 2 * PLANE_U64 + s_sl * 32 + lane;
            __hip_atomic_store(pB, d2, __ATOMIC_RELAXED, __HIP_MEMORY_SCOPE_AGENT);
        }
    };

    const int fro = q * 64 + mm8 * 8;            // A-frag u16 offset inside a k-tile
    publish(0);

    float4 xr[8];
    for (int t = 1; t < T_DIM; ++t) {
        const u64* gbp = gB + (((t - 1) & 1) ? PAR_U64 : 0);
        poll_issue(gbp);                         // loop-top speculative sample (R5-proven)

        if (t < T_DIM - 1) {
            const float* xp = &x[((size_t)(b0 + mm8) * T_DIM + t) * I_DIM];
#pragma unroll
            for (int kt = 0; kt < 4; ++kt) {
                xr[2 * kt]     = *(const float4*)(xp + kt * 32 + q * 8);
                xr[2 * kt + 1] = *(const float4*)(xp + kt * 32 + q * 8 + 4);
            }
        }
        f32x4 xacc0 = {0.f,0.f,0.f,0.f}, xacc1 = {0.f,0.f,0.f,0.f};
#pragma unroll
        for (int kt = 0; kt < 4; ++kt) {
            xacc0 = __builtin_amdgcn_mfma_f32_16x16x32_bf16(xfr[kt], wifr[kt],     xacc0, 0,0,0);
            xacc1 = __builtin_amdgcn_mfma_f32_16x16x32_bf16(xfr[kt], wifr[4 + kt], xacc1, 0,0,0);
        }

        poll_check(t - 1, gbp);                  // usually already satisfied
        unpack();
        bar_lgkm();                              // abuf(a_{t-1}) ready

        f32x4 acc00 = {0.f,0.f,0.f,0.f}, acc01 = {0.f,0.f,0.f,0.f};
        f32x4 acc10 = {0.f,0.f,0.f,0.f}, acc11 = {0.f,0.f,0.f,0.f};
        f32x4 oa    = {0.f,0.f,0.f,0.f};
#pragma unroll
        for (int kt = 0; kt < 32; kt += 2) {
            short8 af0 = *(const short8*)&abuf[kt * 256 + fro];
            short8 af1 = *(const short8*)&abuf[(kt + 1) * 256 + fro];
            acc00 = __builtin_amdgcn_mfma_f32_16x16x32_bf16(af0, wfr[kt],          acc00, 0,0,0);
            acc01 = __builtin_amdgcn_mfma_f32_16x16x32_bf16(af1, wfr[kt + 1],      acc01, 0,0,0);
            acc10 = __builtin_amdgcn_mfma_f32_16x16x32_bf16(af0, wfr[32 + kt],     acc10, 0,0,0);
            acc11 = __builtin_amdgcn_mfma_f32_16x16x32_bf16(af1, wfr[32 + kt + 1], acc11, 0,0,0);
            if ((kt >> 3) == w) {                // fused out(t-1): reuse the A-frags
                oa = __builtin_amdgcn_mfma_f32_16x16x32_bf16(af0, wofr[kt & 7],       oa, 0,0,0);
                oa = __builtin_amdgcn_mfma_f32_16x16x32_bf16(af1, wofr[(kt + 1) & 7], oa, 0,0,0);
            }
        }

        // h update + stage a_t (valid batch rows live in lanes < 32)
#pragma unroll
        for (int nt = 0; nt < 2; ++nt) {
            const f32x4 a0 = nt ? acc10 : acc00;
            const f32x4 a1 = nt ? acc11 : acc01;
            const f32x4 xa = nt ? xacc1 : xacc0;
#pragma unroll
            for (int r = 0; r < 4; ++r) {
                const float z  = xa[r] + a0[r] + a1[r];
                const float hv = (1.0f - ALPHA) * hreg[nt * 4 + r] + ALPHA * z;
                hreg[nt * 4 + r] = hv;
                if (lane < 32) {
                    const unsigned short av = f2b(gvv[nt] * tanh_fast(hv + bvv[nt]));
                    aloc[w * 256 + ((4 * q2 + r) * 4 + nt * 2 + b3) * 8 + mm8] = av;
                }
            }
        }
        publish(t);

        if (lane < 32) {
#pragma unroll
            for (int r = 0; r < 4; ++r)
                opart[w * 128 + (4 * q2 + r) * 16 + n16] = oa[r];
        }
        if (t < T_DIM - 1) {
#pragma unroll
            for (int kt = 0; kt < 4; ++kt)
                xfr[kt] = pack8(xr[2 * kt], xr[2 * kt + 1]);
        }
        bar_lgkm();                              // opart ready (also guards next unpack)
        if (tid < 128) {
            const float s = opart[tid] + opart[128 + tid] + opart[256 + tid] + opart[384 + tid];
            const int m = tid >> 4, c = tid & 15;
            out[((size_t)(b0 + m) * T_DIM + (t - 1)) * O_DIM + ji * 16 + c] = s;
        }
    }

    // epilogue: out[:, 511, :] from a_511 (parity 1)
    {
        const u64* gbe = gB + PAR_U64;
        poll_issue(gbe);
        poll_check(T_DIM - 1, gbe);
        unpack();
        bar_lgkm();
        f32x4 oa = {0.f,0.f,0.f,0.f};
#pragma unroll
        for (int kk = 0; kk < 8; ++kk) {
            short8 af = *(const short8*)&abuf[(w * 8 + kk) * 256 + fro];
            oa = __builtin_amdgcn_mfma_f32_16x16x32_bf16(af, wofr[kk], oa, 0, 0, 0);
        }
        if (lane < 32) {
#pragma unroll
            for (int r = 0; r < 4; ++r)
                opart[w * 128 + (4 * q2 + r) * 16 + n16] = oa[r];
        }
        bar_lgkm();
        if (tid < 128) {
            const float s = opart[tid] + opart[128 + tid] + opart[256 + tid] + opart[384 + tid];
            const int m = tid >> 4, c = tid & 15;
            out[((size_t)(b0 + m) * T_DIM + (T_DIM - 1)) * O_DIM + ji * 16 + c] = s;
        }
    }
}

extern "C" void kernel_launch(void* const* d_in, const int* in_sizes, int n_in,
                              void* d_out, int out_size, void* d_ws, size_t ws_size,
                              hipStream_t stream) {
    const float* x    = (const float*)d_in[0];
    const float* wi   = (const float*)d_in[1];
    const float* wrec = (const float*)d_in[2];
    const float* wout = (const float*)d_in[3];
    const float* bb   = (const float*)d_in[4];
    const float* gg   = (const float*)d_in[5];
    const float* h0   = (const float*)d_in[6];
    float* outp = (float*)d_out;

    u64* aG = (u64*)d_ws;   // exactly 384 KiB (the R1-R5-proven workspace footprint)

    // 0xFF fill: chunk tags 0xFFFF match no t<512
    hipMemsetAsync(d_ws, 0xFF, (size_t)ARENA_U64 * sizeof(u64), stream);
    hipLaunchKernelGGL(rnn_kernel, dim3(NWG), dim3(256), 0, stream,
                       x, wi, wrec, wout, bb, gg, h0, outp, aG);
}

// Round 9
// 1855.438 us; speedup vs baseline: 1.1550x; 1.1550x over previous
//
#include <hip/hip_runtime.h>

#define H 1024
#define I_DIM 128
#define O_DIM 128
#define T_DIM 512
#define ALPHA 0.2f
#define NWG 64            // 4 batch-groups x 16 j-slices (R5-proven geometry)
#define PLANE_U64 2048    // 64 slices x 32 octets, one u64 chunk each
#define GRP_U64   (3 * PLANE_U64)   // 6144 u64 = 48 KB per (parity, group)

typedef short short8 __attribute__((ext_vector_type(8)));
typedef float f32x4 __attribute__((ext_vector_type(4)));
typedef unsigned long long u64;
typedef unsigned long long ull_alias __attribute__((may_alias));

__device__ __forceinline__ unsigned short f2b(float f) {
    union { float f; unsigned u; } x; x.f = f;
    unsigned u = x.u;
    return (unsigned short)((u + 0x7FFFu + ((u >> 16) & 1u)) >> 16);
}
__device__ __forceinline__ float tanh_fast(float x) {
    float e = __expf(2.0f * x);
    return 1.0f - 2.0f * __builtin_amdgcn_rcpf(e + 1.0f);
}
__device__ __forceinline__ short8 ld8f(const float* __restrict__ p) {
    const float4 a = *(const float4*)p;
    const float4 b = *(const float4*)(p + 4);
    short8 r;
    r[0]=(short)f2b(a.x); r[1]=(short)f2b(a.y); r[2]=(short)f2b(a.z); r[3]=(short)f2b(a.w);
    r[4]=(short)f2b(b.x); r[5]=(short)f2b(b.y); r[6]=(short)f2b(b.z); r[7]=(short)f2b(b.w);
    return r;
}
__device__ __forceinline__ short8 pack8(float4 a, float4 b) {
    short8 r;
    r[0]=(short)f2b(a.x); r[1]=(short)f2b(a.y); r[2]=(short)f2b(a.z); r[3]=(short)f2b(a.w);
    r[4]=(short)f2b(b.x); r[5]=(short)f2b(b.y); r[6]=(short)f2b(b.z); r[7]=(short)f2b(b.w);
    return r;
}
// LDS-only barrier (no vmcnt drain) — proven in R5. All barriers hand off LDS.
__device__ __forceinline__ void bar_lgkm() {
    asm volatile("s_waitcnt lgkmcnt(0)\n\ts_barrier" ::: "memory");
}

// Packed-A layout per batch-group: A[m][k] at u16 offset
//   (k>>5)*512 + ((k&31)>>3)*128 + m*8 + (k&7)
// Chunk protocol (R5-proven): slice s=ji*4+w publishes 32 octets as THREE
// self-validating 8B chunks (48b data + 16b tag) at plane_p[s*32+o]; the
// consumer's successful poll IS the fetch.
// R9 chain cuts: (1) abuf double-buffered -> the pre-unpack barrier is GONE
// (1 chain barrier/step); (2) do_out(t-2) moved between poll_issue and
// poll_check so its ~250cy covers the poll-load RT.
__global__ __launch_bounds__(256, 1) void rnn_kernel(
    const float* __restrict__ x, const float* __restrict__ wi,
    const float* __restrict__ wrec, const float* __restrict__ wout,
    const float* __restrict__ bb, const float* __restrict__ gg,
    const float* __restrict__ h0p, float* __restrict__ out,
    u64* __restrict__ aG)
{
    __shared__ unsigned short abuf[2][16384];   // 2 x 32 KB: a_{t-1} double buffer
    __shared__ unsigned short aloc[1024];       // 2 KB: own a_t slice, packed
    __shared__ float opart[4 * 128];            // 2 KB: out k-partials

    const int tid  = threadIdx.x;
    const int w    = tid >> 6, lane = tid & 63;
    const int n    = lane & 15, q = lane >> 4;
    const int grp  = blockIdx.x & 3;
    const int ji   = blockIdx.x >> 2;
    const int j0   = ji * 64;
    const int j    = j0 + w * 16 + n;           // this lane's owned h row
    const int b0   = grp * 16;

    // ---- register-resident weights (f32 -> bf16, once) ----
    short8 wfr[32];                              // wrec B-frags: B[k][j] = wrec[j][k]
#pragma unroll
    for (int kt = 0; kt < 32; ++kt)
        wfr[kt] = ld8f(&wrec[(size_t)j * H + kt * 32 + q * 8]);

    short8 wifr[4];                              // wi B-frags: B[k][j] = wi[k][j]
#pragma unroll
    for (int kt = 0; kt < 4; ++kt) {
        short8 v;
#pragma unroll
        for (int i = 0; i < 8; ++i)
            v[i] = (short)f2b(wi[(size_t)(kt * 32 + q * 8 + i) * H + j]);
        wifr[kt] = v;
    }
    short8 wofr[8];                              // wout B-frags, cols ji*8..+8, zero-pad n>=8
#pragma unroll
    for (int kk = 0; kk < 8; ++kk) {
        short8 v;
        const int kb = (w * 8 + kk) * 32 + q * 8;
#pragma unroll
        for (int i = 0; i < 8; ++i)
            v[i] = (n < 8) ? (short)f2b(wout[(size_t)(kb + i) * O_DIM + ji * 8 + n]) : (short)0;
        wofr[kk] = v;
    }

    const float gv = gg[j], bv = bb[j], h00 = h0p[j];
    float hreg[4];
#pragma unroll
    for (int r = 0; r < 4; ++r) hreg[r] = h00;

    const int kl    = w * 16 + n;                // local k in [0,64)
    const int off_l = (kl >> 5) * 512 + ((kl & 31) >> 3) * 128 + (kl & 7);
    const int s_sl  = ji * 4 + w;                // this wave's slice index

    u64* const gB0 = aG + grp * GRP_U64;            // parity 0
    u64* const gB1 = aG + (4 + grp) * GRP_U64;      // parity 1

    // publish chunk slots (lane-contiguous)
    const int pubA = (lane >> 5) * PLANE_U64 + s_sl * 32 + (lane & 31);  // parts 0/1
    const int pubB = 2 * PLANE_U64 + s_sl * 32 + lane;                    // part 2, lane<32
    const int oA   = lane & 31;

    // consume: load offset perm keeps 512B/instr coalescing; unpack dest LINEAR
    const int perm  = (lane >> 5) * 32 + (lane & 15) * 2 + ((lane >> 4) & 1);
    const int cb    = w * 512 + perm;

    auto publish = [&](int t) {
        asm volatile("s_waitcnt lgkmcnt(0)" ::: "memory");   // own aloc writes done
        const u64 tagv = (u64)(unsigned)t << 48;
        u64* gb = (t & 1) ? gB1 : gB0;
        {
            const ull_alias* opq = (const ull_alias*)&aloc[w * 256 + (oA & 1) * 128 + (oA >> 1) * 8];
            const u64 lo = opq[0], hi = opq[1];
            const u64 d0 = lo & 0x0000FFFFFFFFFFFFull;                        // v0 v1 v2
            const u64 d1 = ((lo >> 48) | (hi << 16)) & 0x0000FFFFFFFFFFFFull; // v3 v4 v5
            __hip_atomic_store(gb + pubA, ((lane < 32) ? d0 : d1) | tagv,
                               __ATOMIC_RELAXED, __HIP_MEMORY_SCOPE_AGENT);
        }
        if (lane < 32) {
            const ull_alias* opq = (const ull_alias*)&aloc[w * 256 + (lane & 1) * 128 + (lane >> 1) * 8];
            const u64 hi = opq[1];
            const u64 d2 = ((hi >> 32) & 0xFFFFFFFFull) | tagv;               // v6 v7
            __hip_atomic_store(gb + pubB, d2, __ATOMIC_RELAXED, __HIP_MEMORY_SCOPE_AGENT);
        }
    };

    u64 pv0[8], pv1[8], pv2[8];

    auto poll_issue = [&](const u64* gb) {
#pragma unroll
        for (int i = 0; i < 8; ++i) {
            pv0[i] = __hip_atomic_load(gb + cb + i * 64,
                                       __ATOMIC_RELAXED, __HIP_MEMORY_SCOPE_AGENT);
            pv1[i] = __hip_atomic_load(gb + PLANE_U64 + cb + i * 64,
                                       __ATOMIC_RELAXED, __HIP_MEMORY_SCOPE_AGENT);
            pv2[i] = __hip_atomic_load(gb + 2 * PLANE_U64 + cb + i * 64,
                                       __ATOMIC_RELAXED, __HIP_MEMORY_SCOPE_AGENT);
        }
    };
    auto poll_check = [&](int tv, const u64* gb) {
        const unsigned tt = (unsigned)tv;
        for (;;) {
            unsigned bad = 0;
#pragma unroll
            for (int i = 0; i < 8; ++i)
                bad |= ((unsigned)(pv0[i] >> 48) ^ tt) | ((unsigned)(pv1[i] >> 48) ^ tt)
                     | ((unsigned)(pv2[i] >> 48) ^ tt);
            if (__all(bad == 0)) break;
            __builtin_amdgcn_s_sleep(1);
            poll_issue(gb);
        }
        asm volatile("" ::: "memory");
    };
    // recombine triples -> abuf[cur], linear contiguous b128 writes
    auto unpack = [&](unsigned short* ab) {
#pragma unroll
        for (int i = 0; i < 8; ++i) {
            const u64 ca = pv0[i], cb_ = pv1[i], cc = pv2[i];
            const u64 w01 = (ca & 0xFFFFFFFFull)
                | (((ca >> 32) & 0xFFFFull) << 32) | ((cb_ & 0xFFFFull) << 48);   // v0..v3
            const u64 w23 = ((cb_ >> 16) & 0xFFFFFFFFull) | (cc << 32);           // v4..v7
            ull_alias* d = (ull_alias*)((char*)ab + w * 8192 + (i * 64 + lane) * 16);
            d[0] = w01; d[1] = w23;
        }
    };

    // out[:, t, ji*8..+8) from the given abuf half (full k=1024 chain)
    auto do_out = [&](int t, const unsigned short* ab) {
        f32x4 oa = {0.f, 0.f, 0.f, 0.f};
#pragma unroll
        for (int kk = 0; kk < 8; ++kk) {
            short8 af = *(const short8*)&ab[(w * 8 + kk) * 512 + lane * 8];
            oa = __builtin_amdgcn_mfma_f32_16x16x32_bf16(af, wofr[kk], oa, 0, 0, 0);
        }
        if (n < 8) {
#pragma unroll
            for (int r = 0; r < 4; ++r) opart[w * 128 + (4 * q + r) * 8 + n] = oa[r];
        }
        bar_lgkm();
        if (tid < 128) {
            float s = opart[tid] + opart[128 + tid] + opart[256 + tid] + opart[384 + tid];
            const int m = tid >> 3, c = tid & 7;
            out[((size_t)(b0 + m) * T_DIM + t) * O_DIM + ji * 8 + c] = s;
        }
    };

    // ---- init: stage + publish a0 = g*tanh(h0+b) (batch-broadcast) ----
    {
        unsigned short a0 = f2b(gv * tanh_fast(h00 + bv));
#pragma unroll
        for (int r = 0; r < 4; ++r) aloc[off_l + (4 * q + r) * 8] = a0;
        publish(0);
    }

    short8 xfr[4];                               // packed x[:,0,:]
#pragma unroll
    for (int kt = 0; kt < 4; ++kt)
        xfr[kt] = ld8f(&x[(size_t)(b0 + n) * T_DIM * I_DIM + kt * 32 + q * 8]);

    float4 xr[8];                                // raw f32 prefetch (issue-early/pack-late)

    for (int t = 1; t < T_DIM; ++t) {
        const u64* gbp = ((t - 1) & 1) ? gB1 : gB0;   // parity of a_{t-1}
        unsigned short* cur  = abuf[(t - 1) & 1];     // unpack target (a_{t-1})
        unsigned short* prev = abuf[t & 1];           // holds a_{t-2}

        // speculative sample first: covered by x-loads, x-MFMAs AND do_out below
        poll_issue(gbp);

        if (t < T_DIM - 1) {
            const float* xp = &x[((size_t)(b0 + n) * T_DIM + t) * I_DIM];
#pragma unroll
            for (int kt = 0; kt < 4; ++kt) {
                xr[2 * kt]     = *(const float4*)(xp + kt * 32 + q * 8);
                xr[2 * kt + 1] = *(const float4*)(xp + kt * 32 + q * 8 + 4);
            }
        }

        // x@wi partials: register-only
        f32x4 acc0 = {0.f,0.f,0.f,0.f}, acc1 = {0.f,0.f,0.f,0.f};
        acc0 = __builtin_amdgcn_mfma_f32_16x16x32_bf16(xfr[0], wifr[0], acc0, 0,0,0);
        acc1 = __builtin_amdgcn_mfma_f32_16x16x32_bf16(xfr[1], wifr[1], acc1, 0,0,0);
        acc0 = __builtin_amdgcn_mfma_f32_16x16x32_bf16(xfr[2], wifr[2], acc0, 0,0,0);
        acc1 = __builtin_amdgcn_mfma_f32_16x16x32_bf16(xfr[3], wifr[3], acc1, 0,0,0);

        // out for step t-2: reads the OTHER abuf half -> no barrier needed before
        // unpack; its MFMAs+opart+store cover the in-flight poll loads.
        if (t >= 2) do_out(t - 2, prev);

        poll_check(t - 1, gbp);   // usually already satisfied
        unpack(cur);
        bar_lgkm();               // the ONE chain barrier: abuf[cur] ready

        // + a_{t-1} @ wrec^T
#pragma unroll
        for (int kt = 0; kt < 32; kt += 2) {
            short8 a0f = *(const short8*)&cur[kt * 512 + lane * 8];
            short8 a1f = *(const short8*)&cur[(kt + 1) * 512 + lane * 8];
            acc0 = __builtin_amdgcn_mfma_f32_16x16x32_bf16(a0f, wfr[kt],     acc0, 0,0,0);
            acc1 = __builtin_amdgcn_mfma_f32_16x16x32_bf16(a1f, wfr[kt + 1], acc1, 0,0,0);
        }

        // h update; stage a_t in aloc (wave-private region), publish immediately
#pragma unroll
        for (int r = 0; r < 4; ++r) {
            float z  = acc0[r] + acc1[r];
            float hv = (1.0f - ALPHA) * hreg[r] + ALPHA * z;
            hreg[r] = hv;
            aloc[off_l + (4 * q + r) * 8] = f2b(gv * tanh_fast(hv + bv));
        }
        publish(t);

        // off critical path: pack the already-loaded x
        if (t < T_DIM - 1) {
#pragma unroll
            for (int kt = 0; kt < 4; ++kt)
                xfr[kt] = pack8(xr[2 * kt], xr[2 * kt + 1]);
        }
    }

    // epilogue: a_511 -> abuf[1]; then out rows 510 (abuf[0]) and 511 (abuf[1])
    {
        poll_issue(gB1);
        poll_check(T_DIM - 1, gB1);
        unpack(abuf[1]);          // a_510 lives in abuf[0] (unpacked at t=511)
        bar_lgkm();
        do_out(T_DIM - 2, abuf[0]);
        bar_lgkm();               // opart reuse guard between the two do_outs
        do_out(T_DIM - 1, abuf[1]);
    }
}

extern "C" void kernel_launch(void* const* d_in, const int* in_sizes, int n_in,
                              void* d_out, int out_size, void* d_ws, size_t ws_size,
                              hipStream_t stream) {
    const float* x    = (const float*)d_in[0];
    const float* wi   = (const float*)d_in[1];
    const float* wrec = (const float*)d_in[2];
    const float* wout = (const float*)d_in[3];
    const float* bb   = (const float*)d_in[4];
    const float* gg   = (const float*)d_in[5];
    const float* h0   = (const float*)d_in[6];
    float* outp = (float*)d_out;

    u64* aG = (u64*)d_ws;   // 2 x 4 x 48 KB = 384 KiB (proven footprint)

    // tags -> 0xFFFF (matches no t<512) so graph replays can't see stale chunks
    hipMemsetAsync(d_ws, 0xFF, (size_t)2 * 4 * GRP_U64 * 8, stream);
    hipLaunchKernelGGL(rnn_kernel, dim3(NWG), dim3(256), 0, stream,
                       x, wi, wrec, wout, bb, gg, h0, outp, aG);
}